// Round 7
// baseline (145.080 us; speedup 1.0000x reference)
//
#include <hip/hip_runtime.h>

// Problem constants (from reference): B=8, T=512, D=512, MAX_LEN = T*15 = 7680
// Dtypes/layout confirmed by R0-R6 forensics: features fp32 (B,T,D),
// durations int32 (B,T), output fp32 (B,MAX_LEN,D), row-major, faithful layout.
// Root cause of R1/R4/R5's identical absmax 5.5: binary search ran 9
// iterations; 512 elements (513 possible answers) need 10. Fixed here.
#define BB 8
#define TT 512
#define DD 512
#define MAX_LEN 7680
#define FPB 30                        // frames per block
#define BPB (MAX_LEN / FPB)           // 256 blocks per batch

__global__ __launch_bounds__(256) void regulate_kernel(
    const float4* __restrict__ feat,   // (B, T, DD/4) as float4
    const int2*   __restrict__ dur2,   // (B, T/2) as int2
    float4*       __restrict__ out)    // (B, MAX_LEN, DD/4) as float4
{
    __shared__ int cum[TT];            // inclusive cumsum of clamped durations
    __shared__ int ps[256];            // pair partial sums for the scan

    const int t    = threadIdx.x;
    const int b    = blockIdx.x / BPB;
    const int base = (blockIdx.x % BPB) * FPB;

    // ---- load 2 durations/thread, clamp(min=1), pairwise inclusive scan ----
    int2 dd = dur2[b * (TT / 2) + t];
    int d0 = dd.x < 1 ? 1 : dd.x;
    int d1 = dd.y < 1 ? 1 : dd.y;
    ps[t] = d0 + d1;
    __syncthreads();
#pragma unroll
    for (int off = 1; off < 256; off <<= 1) {
        int x = (t >= off) ? ps[t - off] : 0;
        __syncthreads();
        ps[t] += x;
        __syncthreads();
    }
    int incl = ps[t];                  // sum of pairs 0..t == cum[2t+1]
    cum[2 * t]     = incl - d1;
    cum[2 * t + 1] = incl;
    __syncthreads();

    const int total = cum[TT - 1];
    const int lane  = t & 127;         // 128 lanes x float4 = one 2 KB row
    const int sub   = t >> 7;          // two frames in flight per iteration

    // ---- produce FPB frames ----
#pragma unroll
    for (int j = 0; j < FPB; j += 2) {
        const int n = base + j + sub;  // output frame index within batch
        float4 val = make_float4(0.f, 0.f, 0.f, 0.f);
        if (n < total) {
            // searchsorted(cum, n, side="right"): first i with cum[i] > n.
            // 513 possible answers -> 10 iterations (9 was the R1-R5 bug).
            // After convergence (lo==hi<=511) extra iters are fixed-point
            // stable: cum[lo] > n holds, branch keeps hi=lo.
            int lo = 0, hi = TT;
#pragma unroll
            for (int s = 0; s < 10; ++s) {
                int mid = (lo + hi) >> 1;
                if (cum[mid] <= n) lo = mid + 1; else hi = mid;
            }
            val = feat[(size_t)(b * TT + lo) * (DD / 4) + lane];
        }
        out[((size_t)b * MAX_LEN + n) * (DD / 4) + lane] = val;
    }
}

extern "C" void kernel_launch(void* const* d_in, const int* in_sizes, int n_in,
                              void* d_out, int out_size, void* d_ws, size_t ws_size,
                              hipStream_t stream) {
    // Select pointers by element count (features = B*T*D = 2097152, dur = 4096)
    const float* feat;
    const int*   dur;
    if (in_sizes[0] == BB * TT) {
        dur  = (const int*)d_in[0];
        feat = (const float*)d_in[1];
    } else {
        feat = (const float*)d_in[0];
        dur  = (const int*)d_in[1];
    }
    float* out = (float*)d_out;        // (B, MAX_LEN, D) fp32

    regulate_kernel<<<BB * BPB, 256, 0, stream>>>(
        (const float4*)feat, (const int2*)dur, (float4*)out);
}